// Round 14
// baseline (388.439 us; speedup 1.0000x reference)
//
#include <hip/hip_runtime.h>
#include <hip/hip_bf16.h>
#include <hip/hip_fp8.h>

typedef __attribute__((ext_vector_type(2))) float f32x2;
typedef __attribute__((ext_vector_type(4))) int i32x4;
typedef __attribute__((ext_vector_type(8))) int i32x8;
typedef __attribute__((ext_vector_type(16))) float f32x16;

#define MARGIN 0.3f
#define BIGF 3.0e38f

#if defined(__has_builtin)
#if __has_builtin(__builtin_amdgcn_cvt_pk_fp8_f32) && \
    __has_builtin(__builtin_amdgcn_cvt_pk_f32_fp8)
#define HAVE_PK_FP8 1
#endif
#endif

__device__ __forceinline__ void gl2lds16(const void* g, void* l) {
    __builtin_amdgcn_global_load_lds(
        (const __attribute__((address_space(1))) void*)g,
        (__attribute__((address_space(3))) void*)l,
        16, 0, 0);
}

// Wave-per-row convert: fp32 -> fp8 e4m3 (OCP) cast, fp32 row norm of the
// fp8-ROUNDED values (consistent with MFMA dots -> exact diagonal), init
// ap/an. (R7-R13-verified; cnt/tilecnt/gbuf are zeroed by hipMemsetAsync.)
__global__ __launch_bounds__(256) void convert_norm_kernel(
    const float* __restrict__ X, unsigned char* __restrict__ Xq,
    float* __restrict__ nrm, unsigned* __restrict__ ap,
    unsigned* __restrict__ an, int K) {
    const int wave = threadIdx.x >> 6, lane = threadIdx.x & 63;
    const int row = blockIdx.x * 4 + wave;
    const float* xr = X + (size_t)row * K;
    unsigned char* xqr = Xq + (size_t)row * K;
    float s = 0.0f;
    for (int c = lane * 8; c < K; c += 64 * 8) {
        float4 v0 = *(const float4*)(xr + c);
        float4 v1 = *(const float4*)(xr + c + 4);
#if defined(HAVE_PK_FP8)
        int w0 = 0, w1 = 0;
        w0 = __builtin_amdgcn_cvt_pk_fp8_f32(v0.x, v0.y, w0, false);
        w0 = __builtin_amdgcn_cvt_pk_fp8_f32(v0.z, v0.w, w0, true);
        w1 = __builtin_amdgcn_cvt_pk_fp8_f32(v1.x, v1.y, w1, false);
        w1 = __builtin_amdgcn_cvt_pk_fp8_f32(v1.z, v1.w, w1, true);
        f32x2 d0 = __builtin_amdgcn_cvt_pk_f32_fp8(w0, false);
        f32x2 d1 = __builtin_amdgcn_cvt_pk_f32_fp8(w0, true);
        f32x2 d2 = __builtin_amdgcn_cvt_pk_f32_fp8(w1, false);
        f32x2 d3 = __builtin_amdgcn_cvt_pk_f32_fp8(w1, true);
        s += d0[0]*d0[0] + d0[1]*d0[1] + d1[0]*d1[0] + d1[1]*d1[1];
        s += d2[0]*d2[0] + d2[1]*d2[1] + d3[0]*d3[0] + d3[1]*d3[1];
        uint2 u; u.x = (unsigned)w0; u.y = (unsigned)w1;
        *(uint2*)(xqr + c) = u;
#else
        float f[8] = {v0.x, v0.y, v0.z, v0.w, v1.x, v1.y, v1.z, v1.w};
        union { unsigned char b[8]; uint2 u; } p;
#pragma unroll
        for (int i = 0; i < 8; i++) {
            __hip_fp8_e4m3 q(f[i]);       // OCP e4m3, RNE+saturate
            p.b[i] = q.__x;
            float d = (float)q;           // decoded value
            s += d * d;
        }
        *(uint2*)(xqr + c) = p.u;
#endif
    }
    for (int off = 32; off > 0; off >>= 1) s += __shfl_xor(s, off, 64);
    if (lane == 0) {
        nrm[row] = s;
        ap[row] = 0u;           // dist_ap >= 0 always (self is a positive)
        an[row] = 0x7F800000u;  // +inf
    }
}

// SPLIT-K TRIANGLE at the R12-verified shape. 528 upper-triangle 128x128
// tiles x 2 K-halves = 1056 blocks = 4.125/CU (R13 proved the 2-barrier
// structure collapses below 4 blocks/CU; R12 proved it works at 4.0).
// Each block runs the R12 loop (byte-identical body) for 8 of 16 BK=128
// iterations, then atomicAdds its fp32 partial G-tile into gbuf (34.6 MB,
// L3-resident, pre-zeroed). A per-tile counter makes the SECOND-finishing
// half run the tile finisher: read summed G (agent-scope), distances +
// label mask + row/col extrema (both directions; triangle), monotone uint
// atomics to ap/an. LAST of 1056 blocks computes the loss.
__global__ __launch_bounds__(256, 4) void gemm_reduce_kernel(
    const unsigned char* __restrict__ Xq, const float* __restrict__ nrm,
    const int* __restrict__ Y, unsigned* __restrict__ ap,
    unsigned* __restrict__ an, unsigned* __restrict__ cnt,
    unsigned* __restrict__ tilecnt, float* __restrict__ gbuf,
    float* __restrict__ out, int N, int K) {
    __shared__ __align__(16) unsigned char sA[128 * 128];  // 16 KB
    __shared__ __align__(16) unsigned char sB[128 * 128];  // 16 KB
    __shared__ int sYr[128], sYc[128];
    __shared__ float sNr[128], sNc[128];
    __shared__ float lsum[4];
    __shared__ unsigned s_done, s_t;

    const int tid = threadIdx.x;
    const int wave = tid >> 6;
    const int lane = tid & 63;
    const int m = lane & 31;   // row within 32x32 subtile / col within subtile
    const int h = lane >> 5;   // k-half (inputs) / row-group (outputs)
    const int wr = wave >> 1;  // wave row (0..1)
    const int wc = wave & 1;   // wave col (0..1)

    const int t = blockIdx.x >> 1;      // tile 0..527
    const int khalf = blockIdx.x & 1;   // K half

    // Upper-triangle decode (r <= j): tiles for col-super j start at j(j+1)/2.
    int j = 0;
    {
        while ((j + 1) * (j + 2) / 2 <= t) j++;
    }
    const int r = t - j * (j + 1) / 2;  // 0..j
    const int rowBase = r * 128;
    const int colBase = j * 128;

    if (tid < 128) {
        sYr[tid] = Y[rowBase + tid];
        sNr[tid] = nrm[rowBase + tid];
    } else {
        int tt = tid - 128;
        sYc[tt] = Y[colBase + tt];
        sNc[tt] = nrm[colBase + tt];
    }

    f32x16 acc[2][2];
#pragma unroll
    for (int si = 0; si < 2; si++)
#pragma unroll
        for (int sj = 0; sj < 2; sj++)
#pragma unroll
            for (int rr = 0; rr < 16; rr++) acc[si][sj][rr] = 0.0f;

    // Staging (R12-verified lane math): lane l covers LDS row l>>3 of an
    // 8-row group, physical 16B chunk l&7, fetching LOGICAL chunk
    // (l&7)^(l>>3) so phys = logical ^ (row&7).
    const int rsub = lane >> 3;
    const int jchunk = (lane & 7) ^ rsub;
    const unsigned char* gA = Xq + (size_t)(rowBase + wave * 32 + rsub) * K + jchunk * 16;
    const unsigned char* gB = Xq + (size_t)(colBase + wave * 32 + rsub) * K + jchunk * 16;
    unsigned char* lA = sA + wave * 4096;  // 32 rows * 128 B
    unsigned char* lB = sB + wave * 4096;
    const size_t g8 = (size_t)8 * K;  // 8 rows, bytes

    const int e = m & 7;             // unswizzle key: row&7 = m&7
    const int nit = K >> 7;          // 16 at K=2048
    const int it0 = khalf * (nit / 2);
    const int it1 = it0 + nit / 2;   // 8 iterations per block

    for (int it = it0; it < it1; it++) {
        const size_t go = (size_t)it * 128;  // 128 k-elems * 1 B
#pragma unroll
        for (int g = 0; g < 4; g++) {
            gl2lds16(gA + go + g * g8, lA + g * 1024);
            gl2lds16(gB + go + g * g8, lB + g * 1024);
        }
        __syncthreads();  // drains vmcnt for gl2lds

#pragma unroll
        for (int s = 0; s < 2; s++) {      // two k64 steps per BK=128
            const int c0 = s * 4 + h * 2;  // logical 16B chunk of this k-half
            i32x8 af[2], bf[2];
#pragma unroll
            for (int si = 0; si < 2; si++) {
                const unsigned char* base = sA + (wr * 64 + si * 32 + m) * 128;
                i32x4 lo = *(const i32x4*)(base + ((c0 ^ e) * 16));
                i32x4 hi = *(const i32x4*)(base + (((c0 + 1) ^ e) * 16));
                af[si] = __builtin_shufflevector(lo, hi, 0, 1, 2, 3, 4, 5, 6, 7);
            }
#pragma unroll
            for (int sj = 0; sj < 2; sj++) {
                const unsigned char* base = sB + (wc * 64 + sj * 32 + m) * 128;
                i32x4 lo = *(const i32x4*)(base + ((c0 ^ e) * 16));
                i32x4 hi = *(const i32x4*)(base + (((c0 + 1) ^ e) * 16));
                bf[sj] = __builtin_shufflevector(lo, hi, 0, 1, 2, 3, 4, 5, 6, 7);
            }
#pragma unroll
            for (int si = 0; si < 2; si++)
#pragma unroll
                for (int sj = 0; sj < 2; sj++)
                    acc[si][sj] = __builtin_amdgcn_mfma_scale_f32_32x32x64_f8f6f4(
                        af[si], bf[sj], acc[si][sj], 0 /*A fmt fp8*/,
                        0 /*B fmt fp8*/, 0, 127 /*scale A = 2^0*/,
                        0, 127 /*scale B = 2^0*/);
        }
        __syncthreads();  // protect single buffer before restage
    }

    // Flush partial G-tile: atomicAdd into gbuf (pre-zeroed; two halves sum).
    // C/D map: rIdx = wr*64 + si*32 + (reg&3)+8*(reg>>2)+4*h, cIdx = wc*64 +
    // sj*32 + m (lanes m=0..31 -> consecutive cIdx: coalesced 128B bursts).
    float* gt = gbuf + (size_t)t * 16384;
#pragma unroll
    for (int si = 0; si < 2; si++)
#pragma unroll
        for (int sj = 0; sj < 2; sj++)
#pragma unroll
            for (int reg = 0; reg < 16; reg++) {
                const int rIdx = wr * 64 + si * 32 + (reg & 3) + 8 * (reg >> 2) + 4 * h;
                const int cIdx = wc * 64 + sj * 32 + m;
                atomicAdd(&gt[rIdx * 128 + cIdx], acc[si][sj][reg]);
            }
    __syncthreads();  // drains vmcnt: all this block's atomicAdds performed

    if (tid == 0) {
        __threadfence();                    // release
        s_t = atomicAdd(&tilecnt[t], 1u);
    }
    __syncthreads();

    if (s_t == 1) {  // SECOND half done -> this block runs the tile finisher
        __threadfence();  // acquire
        // Row pass: thread = (row i2, col-half ch); pair-combine via xor 1.
        {
            const int i2 = tid >> 1, ch = tid & 1;
            const int yrI = sYr[i2];
            const float nrI = sNr[i2];
            float pmx = -1.0f, pmn = BIGF;
            for (int c2 = 0; c2 < 64; c2++) {
                const int c = ch * 64 + c2;
                float g = __hip_atomic_load(&gt[i2 * 128 + c], __ATOMIC_RELAXED,
                                            __HIP_MEMORY_SCOPE_AGENT);
                float d2v = nrI + sNc[c] - 2.0f * g;
                float d = sqrtf(fmaxf(d2v, 0.0f));
                bool same = (yrI == sYc[c]);
                pmx = fmaxf(pmx, same ? d : -1.0f);
                pmn = fminf(pmn, same ? BIGF : d);
            }
            pmx = fmaxf(pmx, __shfl_xor(pmx, 1, 64));
            pmn = fminf(pmn, __shfl_xor(pmn, 1, 64));
            if (ch == 0) {  // non-negative floats: uint cmp == float cmp
                atomicMax(&ap[rowBase + i2], __float_as_uint(fmaxf(pmx, 0.0f)));
                atomicMin(&an[rowBase + i2], __float_as_uint(pmn));
            }
        }
        // Col pass (triangle symmetry: d(i,j)=d(j,i)).
        {
            const int c2 = tid >> 1, rh = tid & 1;
            const int ycI = sYc[c2];
            const float ncI = sNc[c2];
            float pmx = -1.0f, pmn = BIGF;
            for (int s2 = 0; s2 < 64; s2++) {
                const int i = rh * 64 + s2;
                float g = __hip_atomic_load(&gt[i * 128 + c2], __ATOMIC_RELAXED,
                                            __HIP_MEMORY_SCOPE_AGENT);
                float d2v = sNr[i] + ncI - 2.0f * g;
                float d = sqrtf(fmaxf(d2v, 0.0f));
                bool same = (sYr[i] == ycI);
                pmx = fmaxf(pmx, same ? d : -1.0f);
                pmn = fminf(pmn, same ? BIGF : d);
            }
            pmx = fmaxf(pmx, __shfl_xor(pmx, 1, 64));
            pmn = fminf(pmn, __shfl_xor(pmn, 1, 64));
            if (rh == 0) {
                atomicMax(&ap[colBase + c2], __float_as_uint(fmaxf(pmx, 0.0f)));
                atomicMin(&an[colBase + c2], __float_as_uint(pmn));
            }
        }
    }

    // Global loss finalize: every block increments cnt AFTER its (possible)
    // finisher work; the block seeing all others done computes the loss.
    __syncthreads();
    if (tid == 0) {
        __threadfence();
        s_done = atomicAdd(cnt, 1u);
    }
    __syncthreads();
    if (s_done == gridDim.x - 1) {
        __threadfence();
        float s = 0.0f;
        for (int i = tid; i < N; i += 256) {
            unsigned ua = __hip_atomic_load(&ap[i], __ATOMIC_RELAXED,
                                            __HIP_MEMORY_SCOPE_AGENT);
            unsigned ub = __hip_atomic_load(&an[i], __ATOMIC_RELAXED,
                                            __HIP_MEMORY_SCOPE_AGENT);
            s += fmaxf(__uint_as_float(ua) - __uint_as_float(ub) + MARGIN, 0.0f);
        }
        for (int off = 32; off > 0; off >>= 1) s += __shfl_xor(s, off, 64);
        if (lane == 0) lsum[wave] = s;
        __syncthreads();
        if (tid == 0)
            out[0] = (lsum[0] + lsum[1] + lsum[2] + lsum[3]) / (float)N;
    }
}

extern "C" void kernel_launch(void* const* d_in, const int* in_sizes, int n_in,
                              void* d_out, int out_size, void* d_ws, size_t ws_size,
                              hipStream_t stream) {
    const float* X = (const float*)d_in[0];
    const int* Y = (const int*)d_in[1];
    float* out = (float*)d_out;
    const int N = in_sizes[1];          // 4096
    const int K = in_sizes[0] / N;      // 2048

    const int NB = N / 128;
    const int ntiles = NB * (NB + 1) / 2;  // 528

    char* ws = (char*)d_ws;
    unsigned char* Xq = (unsigned char*)ws;                   // N*K bytes
    float* nrm = (float*)(ws + (size_t)N * K);
    unsigned* ap = (unsigned*)((char*)nrm + (size_t)N * 4);
    unsigned* an = (unsigned*)((char*)ap + (size_t)N * 4);
    unsigned* cnt = (unsigned*)((char*)an + (size_t)N * 4);
    unsigned* tilecnt = cnt + 1;
    float* gbuf = (float*)((char*)tilecnt + (size_t)ntiles * 4);

    // Zero cnt + tilecnt + gbuf in one async memset (graph-capture legal).
    const size_t zbytes = 4 + (size_t)ntiles * 4 + (size_t)ntiles * 16384 * 4;
    hipMemsetAsync(cnt, 0, zbytes, stream);

    convert_norm_kernel<<<N / 4, 256, 0, stream>>>(X, Xq, nrm, ap, an, K);
    gemm_reduce_kernel<<<ntiles * 2, 256, 0, stream>>>(Xq, nrm, Y, ap, an, cnt,
                                                       tilecnt, gbuf, out, N, K);
}